// Round 11
// baseline (132.952 us; speedup 1.0000x reference)
//
#include <hip/hip_runtime.h>
#include <math.h>

#define ALPHA 8.3f
// Per phase (32 ch): X = 4 planes x 264 slices (4 rows x 66 cols) x 16 B = 16,896 B
// (granule = 8 consecutive channels, bf16, of one halo pixel)
// W = 36 frags (9 taps x 2 mt x 2 kc) x 64 lanes x 16 B = 36,864 B
#define XSZ   16896
#define WSZ   36864
#define BUFSZ 53760   // XSZ + WSZ; double-buffered -> 107,520 B LDS (1 block/CU)

typedef short v8s  __attribute__((ext_vector_type(8)));
typedef float v16f __attribute__((ext_vector_type(16)));
typedef float v4f  __attribute__((ext_vector_type(4)));

static __device__ __forceinline__ unsigned short f2bf(float f) {
    unsigned int u = __float_as_uint(f);
    u = (u + 0x7fffu + ((u >> 16) & 1u)) >> 16;   // RNE
    return (unsigned short)u;
}

static __device__ __forceinline__ void async16(const void* g, void* l) {
    __builtin_amdgcn_global_load_lds(
        (const __attribute__((address_space(1))) unsigned int*)g,
        (__attribute__((address_space(3))) unsigned int*)l, 16, 0, 0);
}

// Weight pre-swizzle (v12 layout, verified):
//   F = ((ss*9 + tap)*2 + mt)*2 + kc; wt[F*512 + lane*8 + j];
//   o = mt*32+(lane&31), cin = ss*32 + kc*16 + (lane>>5)*8 + j.
// Per ss one contiguous 36,864 B region, DMA-copied linearly by the main kernel.
__global__ __launch_bounds__(256) void prep_weights(const float* __restrict__ w,
                                                    unsigned short* __restrict__ wt) {
    const int i = blockIdx.x * 256 + threadIdx.x;
    if (i >= 294912) return;
    const int j    = i & 7;
    const int lane = (i >> 3) & 63;
    const int F    = i >> 9;          // 0..575
    const int kc   = F & 1;
    const int mt   = (F >> 1) & 1;
    const int tq   = F >> 2;          // 0..143
    const int tap  = tq % 9;
    const int ss   = tq / 9;
    const int o    = mt * 32 + (lane & 31);
    const int cin  = ss * 32 + kc * 16 + (lane >> 5) * 8 + j;
    wt[i] = f2bf(w[(o * 512 + cin) * 9 + tap]);
}

// Main v15 = v12 compute/schedule with the NHWC-cast kernel FUSED IN:
// X is reg-staged straight from fp32 NCHW x (loads for phase ss+1 issue right after
// the barrier, convert+pack+ds_write after the MFMA block -> flight hides under
// compute). Same f2bf RNE per element as the old cast -> bit-identical bf16 inputs
// -> bit-identical output. Removes the x2 intermediate (67 MB W+R), the cast
// dispatch, and zbuf. W staging via global_load_lds unchanged (v12).
// 256 blocks x 384 thr (6 waves = rt(2) x di(3)); block = (b, 2 rows, 64 cols),
// all 64 Cout, K=512 over 16 phases of 32 ch; __syncthreads phase separator (v12's
// schedule -- v14's counted-vmcnt was a proven null with prefetch depth 1).
__global__ __launch_bounds__(384)
void depthconv_v15(const float* __restrict__ x,
                   const float* __restrict__ depth,
                   const unsigned short* __restrict__ wt,
                   float* __restrict__ out) {
    __shared__ __align__(16) char smem[2 * BUFSZ];   // 107,520 B (epilogue reuses)

    // XCD-swizzled decode: xcd owns row-tiles [xcd*4, xcd*4+4) for all b
    const int bx   = blockIdx.x;
    const int xcd  = bx & 7;
    const int i0   = bx >> 3;            // 0..31
    const int b    = i0 & 7;
    const int h0   = (xcd * 4 + (i0 >> 3)) * 2;   // 0..62, 2 rows per block

    const int tid  = threadIdx.x;
    const int wid  = tid >> 6;           // 0..5
    const int lane = tid & 63;
    const int l31  = lane & 31;
    const int half = lane >> 5;
    const int rt   = wid & 1;            // wave's row within the 2-row tile
    const int di   = wid >> 1;           // kernel row 0..2

    // ---- per-thread X staging descriptors (3 granules, phase-invariant) ----
    // granule g_i = it*384+tid (< 1056): plane p = g_i/264 (8-ch group), s = g_i%264,
    // r = s/66, c = s%66 -> pixel (h0-1+r, c-1). fp32 src: x[b][p*8+e][hh][ww], e=0..7.
    const float* xb = x + (size_t)b * 2097152;
    const float* xsrc[3];
    int  goff[3];
    bool gval[3], gact[3];
#pragma unroll
    for (int it = 0; it < 3; ++it) {
        const int g_i = it * 384 + tid;
        const bool act = (g_i < 1056);
        const int p_ = g_i / 264;
        const int s_ = g_i - p_ * 264;
        const int r_ = s_ / 66, c_ = s_ - r_ * 66;
        const int hh = h0 - 1 + r_, ww = c_ - 1;
        const bool val = act && hh >= 0 && hh < 64 && ww >= 0 && ww < 64;
        gact[it] = act;
        gval[it] = val;
        goff[it] = g_i * 16;
        xsrc[it] = val ? (xb + (size_t)(p_ * 8) * 4096 + hh * 64 + ww) : xb;
    }

    // XLOAD: issue 24 fp32 loads for phase SS into regs (flight hides under compute)
#define XLOAD(SS, V)                                                             \
    {                                                                            \
        const size_t adv = (size_t)(SS) * 131072;   /* 32 ch * 4096 floats */    \
        _Pragma("unroll")                                                        \
        for (int it = 0; it < 3; ++it)                                           \
            _Pragma("unroll")                                                    \
            for (int e = 0; e < 8; ++e)                                          \
                V[it][e] = gval[it] ? xsrc[it][adv + (size_t)e * 4096] : 0.f;    \
    }
    // XWRITE: f2bf + pack + ds_write_b128 (linear granule layout, conflict-free)
#define XWRITE(V, BSEL)                                                          \
    {                                                                            \
        char* dx = smem + (BSEL) * BUFSZ;                                        \
        _Pragma("unroll")                                                        \
        for (int it = 0; it < 3; ++it)                                           \
            if (gact[it]) {                                                      \
                uint4 u;                                                         \
                u.x = f2bf(V[it][0]) | ((unsigned)f2bf(V[it][1]) << 16);         \
                u.y = f2bf(V[it][2]) | ((unsigned)f2bf(V[it][3]) << 16);         \
                u.z = f2bf(V[it][4]) | ((unsigned)f2bf(V[it][5]) << 16);         \
                u.w = f2bf(V[it][6]) | ((unsigned)f2bf(V[it][7]) << 16);         \
                *(uint4*)(dx + goff[it]) = u;                                    \
            }                                                                    \
    }
    // W staging via DMA (v12): 6 async16/thread, linear dests
#define WISSUE(SS, BSEL)                                                         \
    {                                                                            \
        char* dw = smem + (BSEL) * BUFSZ + XSZ;                                  \
        const char* ws = (const char*)wt + (size_t)(SS) * WSZ;                   \
        _Pragma("unroll")                                                        \
        for (int k = 0; k < 6; ++k)                                              \
            async16(ws + (size_t)(k * 384 + tid) * 16,                           \
                    dw + (k * 384 + tid) * 16);                                  \
    }

    // ---- gates gt[n][dj] (fp32, OOB depth = 0; verified convention) ----
    float gt[2][3];
    {
        const float* dp = depth + (size_t)b * 4096;
        const int hq = h0 + rt;
        const int hn = hq + di - 1;
#pragma unroll
        for (int n = 0; n < 2; ++n) {
            const int wq = n * 32 + l31;
            const float d0 = dp[hq * 64 + wq];
#pragma unroll
            for (int dj = 0; dj < 3; ++dj) {
                const int wn = wq + dj - 1;
                const float dn = (hn >= 0 && hn < 64 && wn >= 0 && wn < 64)
                                     ? dp[hn * 64 + wn] : 0.f;
                gt[n][dj] = __expf(-ALPHA * fabsf(d0 - dn));
            }
        }
    }

    v16f a00[3], a01[3], a10[3], a11[3];   // acc[dj][n][mt]: aNM, N=n, M=mt
#pragma unroll
    for (int d = 0; d < 3; ++d)
#pragma unroll
        for (int r = 0; r < 16; ++r) { a00[d][r] = 0.f; a01[d][r] = 0.f;
                                       a10[d][r] = 0.f; a11[d][r] = 0.f; }

    // per-thread LDS read bases (buffer offset added per phase) -- v12 verified
    const int aOff = XSZ + di * 12288 + lane * 16;              // + ((dj*2+mt)*2+kc)*1024
    const int bOff = (half * 264 + (rt + di) * 66 + l31) * 16;  // + kc*8448 + (n*32+dj)*16

    // ---- prologue: stage phase 0 ----
    float v[3][8];
    WISSUE(0, 0);
    XLOAD(0, v);
    XWRITE(v, 0);

    for (int ss = 0; ss < 16; ++ss) {
        __syncthreads();                 // drains W-DMA(ss), fences X writes + prev reads
        const int cur = ss & 1;
        const int nxt = cur ^ 1;
        if (ss < 15) {
            WISSUE(ss + 1, nxt);         // DMA flies under compute(ss)
            XLOAD(ss + 1, v);            // fp32 loads fly under compute(ss)
        }
        const char* ba = smem + cur * BUFSZ + aOff;
        const char* bb = smem + cur * BUFSZ + bOff;
#pragma unroll
        for (int dj = 0; dj < 3; ++dj) {
#pragma unroll
            for (int kc = 0; kc < 2; ++kc) {
                const v8s w0 = *(const v8s*)(ba + ((dj * 2 + 0) * 2 + kc) * 1024);
                const v8s w1 = *(const v8s*)(ba + ((dj * 2 + 1) * 2 + kc) * 1024);
                const v8s x0 = *(const v8s*)(bb + kc * 8448 + (0 * 32 + dj) * 16);
                const v8s x1 = *(const v8s*)(bb + kc * 8448 + (1 * 32 + dj) * 16);
                a00[dj] = __builtin_amdgcn_mfma_f32_32x32x16_bf16(w0, x0, a00[dj], 0, 0, 0);
                a01[dj] = __builtin_amdgcn_mfma_f32_32x32x16_bf16(w1, x0, a01[dj], 0, 0, 0);
                a10[dj] = __builtin_amdgcn_mfma_f32_32x32x16_bf16(w0, x1, a10[dj], 0, 0, 0);
                a11[dj] = __builtin_amdgcn_mfma_f32_32x32x16_bf16(w1, x1, a11[dj], 0, 0, 0);
            }
        }
        if (ss < 15) XWRITE(v, nxt);     // lands before next barrier opens phase ss+1
    }

    // ---- epilogue: gate-combine per tap into [0] slot (in place) ----
#pragma unroll
    for (int r = 0; r < 16; ++r) {
        a00[0][r] = gt[0][0] * a00[0][r];
        a00[0][r] = fmaf(gt[0][1], a00[1][r], a00[0][r]);
        a00[0][r] = fmaf(gt[0][2], a00[2][r], a00[0][r]);
        a01[0][r] = gt[0][0] * a01[0][r];
        a01[0][r] = fmaf(gt[0][1], a01[1][r], a01[0][r]);
        a01[0][r] = fmaf(gt[0][2], a01[2][r], a01[0][r]);
        a10[0][r] = gt[1][0] * a10[0][r];
        a10[0][r] = fmaf(gt[1][1], a10[1][r], a10[0][r]);
        a10[0][r] = fmaf(gt[1][2], a10[2][r], a10[0][r]);
        a11[0][r] = gt[1][0] * a11[0][r];
        a11[0][r] = fmaf(gt[1][1], a11[1][r], a11[0][r]);
        a11[0][r] = fmaf(gt[1][2], a11[2][r], a11[0][r]);
    }

    // ---- di-reduction in LDS (RMW, 2 x 16 KB regions, qd-major = conflict-free) ----
    __syncthreads();
    float* red = (float*)smem;
    const int rbase = rt * 4096 + lane * 4;
#define EPI_STORE(ACC, N, MT)                                                    \
    _Pragma("unroll")                                                            \
    for (int qd = 0; qd < 4; ++qd) {                                             \
        v4f vv; vv[0] = ACC[0][qd * 4]; vv[1] = ACC[0][qd * 4 + 1];              \
        vv[2] = ACC[0][qd * 4 + 2]; vv[3] = ACC[0][qd * 4 + 3];                  \
        *(v4f*)&red[rbase + ((N) * 2 + (MT)) * 1024 + qd * 256] = vv;            \
    }
#define EPI_ADD(ACC, N, MT)                                                      \
    _Pragma("unroll")                                                            \
    for (int qd = 0; qd < 4; ++qd) {                                             \
        v4f vv = *(const v4f*)&red[rbase + ((N) * 2 + (MT)) * 1024 + qd * 256];  \
        vv[0] += ACC[0][qd * 4];     vv[1] += ACC[0][qd * 4 + 1];                \
        vv[2] += ACC[0][qd * 4 + 2]; vv[3] += ACC[0][qd * 4 + 3];                \
        *(v4f*)&red[rbase + ((N) * 2 + (MT)) * 1024 + qd * 256] = vv;            \
    }
    if (di == 2) {
        EPI_STORE(a00, 0, 0) EPI_STORE(a01, 0, 1) EPI_STORE(a10, 1, 0) EPI_STORE(a11, 1, 1)
    }
    __syncthreads();
    if (di == 1) {
        EPI_ADD(a00, 0, 0) EPI_ADD(a01, 0, 1) EPI_ADD(a10, 1, 0) EPI_ADD(a11, 1, 1)
    }
    __syncthreads();
    if (di == 0) {
        float* ob = out + (size_t)b * 262144 + (h0 + rt) * 64;
#define EPI_OUT(ACC, N, MT)                                                      \
    _Pragma("unroll")                                                            \
    for (int qd = 0; qd < 4; ++qd) {                                             \
        const v4f vv = *(const v4f*)&red[rbase + ((N) * 2 + (MT)) * 1024 + qd * 256]; \
        _Pragma("unroll")                                                        \
        for (int j = 0; j < 4; ++j) {                                            \
            const int rg = qd * 4 + j;                                           \
            const int o = (MT) * 32 + (rg & 3) + 8 * (rg >> 2) + 4 * half;       \
            ob[(size_t)o * 4096 + (N) * 32 + l31] = ACC[0][rg] + vv[j];          \
        }                                                                        \
    }
        EPI_OUT(a00, 0, 0) EPI_OUT(a01, 0, 1) EPI_OUT(a10, 1, 0) EPI_OUT(a11, 1, 1)
    }
}

extern "C" void kernel_launch(void* const* d_in, const int* in_sizes, int n_in,
                              void* d_out, int out_size, void* d_ws, size_t ws_size,
                              hipStream_t stream) {
    const float* x      = (const float*)d_in[0];
    const float* depth  = (const float*)d_in[1];
    const float* weight = (const float*)d_in[2];
    float* out = (float*)d_out;

    unsigned short* wtb = (unsigned short*)d_ws;   // 589,824 B weight staging

    prep_weights<<<1152, 256, 0, stream>>>(weight, wtb);
    depthconv_v15<<<256, 384, 0, stream>>>(x, depth, wtb, out);
}

// Round 12
// 122.093 us; speedup vs baseline: 1.0889x; 1.0889x over previous
//
#include <hip/hip_runtime.h>
#include <math.h>

#define ALPHA 8.3f
// Per phase (32 ch): X = 4 planes x 264 slices (4 rows x 66 cols) x 16 B = 16,896 B
// W = 36 frags (9 taps x 2 mt x 2 kc) x 64 lanes x 16 B = 36,864 B
#define XSZ   16896
#define WSZ   36864
#define BUFSZ 53760   // XSZ + WSZ; double-buffered -> 107,520 B LDS (1 block/CU)

typedef short v8s  __attribute__((ext_vector_type(8)));
typedef float v16f __attribute__((ext_vector_type(16)));
typedef float v4f  __attribute__((ext_vector_type(4)));

static __device__ __forceinline__ unsigned short f2bf(float f) {
    unsigned int u = __float_as_uint(f);
    u = (u + 0x7fffu + ((u >> 16) & 1u)) >> 16;   // RNE
    return (unsigned short)u;
}

static __device__ __forceinline__ void async16(const void* g, void* l) {
    __builtin_amdgcn_global_load_lds(
        (const __attribute__((address_space(1))) unsigned int*)g,
        (__attribute__((address_space(3))) unsigned int*)l, 16, 0, 0);
}

// Weight pre-swizzle (v12 layout, verified):
//   F = ((ss*9 + tap)*2 + mt)*2 + kc; wt[F*512 + lane*8 + j];
//   o = mt*32+(lane&31), cin = ss*32 + kc*16 + (lane>>5)*8 + j.
__global__ __launch_bounds__(256) void prep_weights(const float* __restrict__ w,
                                                    unsigned short* __restrict__ wt) {
    const int i = blockIdx.x * 256 + threadIdx.x;
    if (i >= 294912) return;
    const int j    = i & 7;
    const int lane = (i >> 3) & 63;
    const int F    = i >> 9;          // 0..575
    const int kc   = F & 1;
    const int mt   = (F >> 1) & 1;
    const int tq   = F >> 2;          // 0..143
    const int tap  = tq % 9;
    const int ss   = tq / 9;
    const int o    = mt * 32 + (lane & 31);
    const int cin  = ss * 32 + kc * 16 + (lane >> 5) * 8 + j;
    wt[i] = f2bf(w[(o * 512 + cin) * 9 + tap]);
}

// Main v16: fused cast (v15) with the two v15 diseases fixed:
//  - 12 waves (768 thr) = mt(2) x rt(2) x di(3); per-wave acc = 6 v16f (96 AGPR);
//    total regs fit the 3-waves/SIMD cap -> NO spill (v15: 128-cap spill, WRITE +6.7MB)
//  - depth-2 X prefetch + counted vmcnt: X(ss+2) loads fly during phase ss; vmcnt
//    never drains to 0 in-loop. Uniform counts: 16 X-loads + 3 W-DMA per thread/phase
//    (slot-1 duplicated for tid>=288).
// Per-acc K-chain (ss->dj->kc), gate-combine and di-reduction identical to v12
// -> bit-identical numerics. Gates computed in the epilogue.
__global__ __launch_bounds__(768, 3)
void depthconv_v16(const float* __restrict__ x,
                   const float* __restrict__ depth,
                   const unsigned short* __restrict__ wt,
                   float* __restrict__ out) {
    __shared__ __align__(16) char smem[2 * BUFSZ];   // 107,520 B (epilogue reuses)

    // XCD-swizzled decode: xcd owns row-tiles [xcd*4, xcd*4+4) for all b
    const int bx   = blockIdx.x;
    const int xcd  = bx & 7;
    const int i0   = bx >> 3;            // 0..31
    const int b    = i0 & 7;
    const int h0   = (xcd * 4 + (i0 >> 3)) * 2;   // 0..62, 2 rows per block

    const int tid  = threadIdx.x;
    const int wid  = tid >> 6;           // 0..11
    const int lane = tid & 63;
    const int l31  = lane & 31;
    const int half = lane >> 5;
    const int mt   = wid & 1;
    const int rt   = (wid >> 1) & 1;     // wave's row within the 2-row tile
    const int di   = wid >> 2;           // kernel row 0..2

    const float* xb = x + (size_t)b * 2097152;   // fp32 NCHW image

    // ---- X slot descriptors (phase-invariant). granule g (0..1055):
    // plane p = g/264 (8-ch group), s = g%264, r = s/66, c = s%66 -> pixel (h0-1+r, c-1).
    // slot0: g = tid (<768). slot1: g = 768+tid for tid<288, else duplicate g=tid
    // (keeps vmem count wave-uniform; result discarded).
    int goff0, goff1; bool val0, val1, act1;
    const float* pX0; const float* pX1;
    {
        const int g0 = tid;
        const int p0 = g0 / 264, s0 = g0 - p0 * 264;
        const int r0 = s0 / 66,  c0 = s0 - r0 * 66;
        const int hh0 = h0 - 1 + r0, ww0 = c0 - 1;
        val0  = (hh0 >= 0 && hh0 < 64 && ww0 >= 0 && ww0 < 64);
        goff0 = g0 * 16;
        pX0   = val0 ? (xb + (size_t)(p0 * 8) * 4096 + hh0 * 64 + ww0) : xb;

        act1 = (tid < 288);
        const int g1 = act1 ? (768 + tid) : tid;
        const int p1 = g1 / 264, s1 = g1 - p1 * 264;
        const int r1 = s1 / 66,  c1 = s1 - r1 * 66;
        const int hh1 = h0 - 1 + r1, ww1 = c1 - 1;
        val1  = (hh1 >= 0 && hh1 < 64 && ww1 >= 0 && ww1 < 64);
        goff1 = g1 * 16;
        pX1   = val1 ? (xb + (size_t)(p1 * 8) * 4096 + hh1 * 64 + ww1) : xb;
    }
    const char* pW = (const char*)wt;

    // XLOAD: 16 fp32 loads (8 per slot), running pointers advance 32 ch per call
#define XLOAD(V)                                                                 \
    {                                                                            \
        _Pragma("unroll")                                                        \
        for (int e = 0; e < 8; ++e) V[e]     = pX0[(size_t)e * 4096];            \
        _Pragma("unroll")                                                        \
        for (int e = 0; e < 8; ++e) V[8 + e] = pX1[(size_t)e * 4096];            \
        pX0 += 131072; pX1 += 131072;                                            \
    }
    // XWRITE: f2bf + pack + zero-invalid + ds_write_b128 (linear granules)
#define XWRITE(V, BSEL)                                                          \
    {                                                                            \
        char* dx = smem + (BSEL) * BUFSZ;                                        \
        uint4 u0;                                                                \
        u0.x = f2bf(V[0]) | ((unsigned)f2bf(V[1]) << 16);                        \
        u0.y = f2bf(V[2]) | ((unsigned)f2bf(V[3]) << 16);                        \
        u0.z = f2bf(V[4]) | ((unsigned)f2bf(V[5]) << 16);                        \
        u0.w = f2bf(V[6]) | ((unsigned)f2bf(V[7]) << 16);                        \
        if (!val0) { u0.x = 0u; u0.y = 0u; u0.z = 0u; u0.w = 0u; }               \
        *(uint4*)(dx + goff0) = u0;                                              \
        if (act1) {                                                              \
            uint4 u1;                                                            \
            u1.x = f2bf(V[8])  | ((unsigned)f2bf(V[9])  << 16);                  \
            u1.y = f2bf(V[10]) | ((unsigned)f2bf(V[11]) << 16);                  \
            u1.z = f2bf(V[12]) | ((unsigned)f2bf(V[13]) << 16);                  \
            u1.w = f2bf(V[14]) | ((unsigned)f2bf(V[15]) << 16);                  \
            if (!val1) { u1.x = 0u; u1.y = 0u; u1.z = 0u; u1.w = 0u; }           \
            *(uint4*)(dx + goff1) = u1;                                          \
        }                                                                        \
    }
    // W staging: 3 async16/thread (2304 = 3*768 exact), wave-uniform linear dests
#define WISSUE(BSEL)                                                             \
    {                                                                            \
        char* dw = smem + (BSEL) * BUFSZ + XSZ;                                  \
        _Pragma("unroll")                                                        \
        for (int k = 0; k < 3; ++k)                                              \
            async16(pW + (size_t)(k * 768 + tid) * 16,                           \
                    dw + (k * 768 + tid) * 16);                                  \
        pW += WSZ;                                                               \
    }

    v16f A0[3], A1[3];   // acc[dj][n]: A0 = n0, A1 = n1 (own mt only)
#pragma unroll
    for (int d = 0; d < 3; ++d)
#pragma unroll
        for (int r = 0; r < 16; ++r) { A0[d][r] = 0.f; A1[d][r] = 0.f; }

    // LDS read bases: W frag offset = di*12288 + dj*4096 + mt*2048 + kc*1024
    const int aOff = XSZ + di * 12288 + mt * 2048 + lane * 16;
    const int bOff = (half * 264 + (rt + di) * 66 + l31) * 16;  // + kc*8448 + (n*32+dj)*16

#define COMPUTE(BSEL)                                                            \
    {                                                                            \
        const char* ba = smem + (BSEL) * BUFSZ + aOff;                           \
        const char* bb = smem + (BSEL) * BUFSZ + bOff;                           \
        _Pragma("unroll")                                                        \
        for (int dj = 0; dj < 3; ++dj)                                           \
            _Pragma("unroll")                                                    \
            for (int kc = 0; kc < 2; ++kc) {                                     \
                const v8s wv = *(const v8s*)(ba + dj * 4096 + kc * 1024);        \
                const v8s x0 = *(const v8s*)(bb + kc * 8448 + dj * 16);          \
                const v8s x1 = *(const v8s*)(bb + kc * 8448 + 512 + dj * 16);    \
                A0[dj] = __builtin_amdgcn_mfma_f32_32x32x16_bf16(wv, x0, A0[dj], 0, 0, 0); \
                A1[dj] = __builtin_amdgcn_mfma_f32_32x32x16_bf16(wv, x1, A1[dj], 0, 0, 0); \
            }                                                                    \
    }

    float vA[16], vB[16];

    // ---- prologue: X(0)->vA, W(0)->buf0, X(1)->vB; write X(0); open buf0 ----
    XLOAD(vA);                                            // 16 vmem
    WISSUE(0);                                            // +3  (buf0)
    XLOAD(vB);                                            // +16
    asm volatile("s_waitcnt vmcnt(19)" ::: "memory");     // X(0) landed
    XWRITE(vA, 0);
    asm volatile("s_waitcnt vmcnt(16) lgkmcnt(0)" ::: "memory");   // W(0) landed
    __builtin_amdgcn_s_barrier();
    __builtin_amdgcn_sched_barrier(0);

    // standard phase: stage W(ss+1)+X(ss+2), compute buf[cur], write X(ss+1)
#define PHASE_STD(CUR, VNEXT, VFREE)                                             \
    {                                                                            \
        WISSUE(CUR ^ 1);                                  /* W(ss+1) -> nxt */   \
        XLOAD(VFREE);                                     /* X(ss+2) */          \
        COMPUTE(CUR);                                                            \
        asm volatile("s_waitcnt vmcnt(19)" ::: "memory"); /* X(ss+1) landed */   \
        XWRITE(VNEXT, CUR ^ 1);                                                  \
        asm volatile("s_waitcnt vmcnt(16) lgkmcnt(0)" ::: "memory");             \
        __builtin_amdgcn_s_barrier();                                            \
        __builtin_amdgcn_sched_barrier(0);                                       \
    }

    for (int sp = 0; sp < 7; ++sp) {      // ss = 0..13
        PHASE_STD(0, vB, vA);
        PHASE_STD(1, vA, vB);
    }
    // ss = 14 (cur=0): no XLOAD; drain W(15) before barrier
    WISSUE(1);                                            // W(15) -> buf1
    COMPUTE(0);
    asm volatile("s_waitcnt vmcnt(3)" ::: "memory");      // X(15)=vB landed
    XWRITE(vB, 1);
    asm volatile("s_waitcnt vmcnt(0) lgkmcnt(0)" ::: "memory");    // W(15) landed
    __builtin_amdgcn_s_barrier();
    __builtin_amdgcn_sched_barrier(0);
    // ss = 15
    COMPUTE(1);

    // ---- epilogue: gates (depth loads safely after all counted waits) ----
    float gt[2][3];
    {
        const float* dp = depth + (size_t)b * 4096;
        const int hq = h0 + rt;
        const int hn = hq + di - 1;
#pragma unroll
        for (int n = 0; n < 2; ++n) {
            const int wq = n * 32 + l31;
            const float d0 = dp[hq * 64 + wq];
#pragma unroll
            for (int dj = 0; dj < 3; ++dj) {
                const int wn = wq + dj - 1;
                const float dn = (hn >= 0 && hn < 64 && wn >= 0 && wn < 64)
                                     ? dp[hn * 64 + wn] : 0.f;
                gt[n][dj] = __expf(-ALPHA * fabsf(d0 - dn));
            }
        }
    }

    // gate-combine per tap into [0] slot (v12 order)
#pragma unroll
    for (int r = 0; r < 16; ++r) {
        A0[0][r] = gt[0][0] * A0[0][r];
        A0[0][r] = fmaf(gt[0][1], A0[1][r], A0[0][r]);
        A0[0][r] = fmaf(gt[0][2], A0[2][r], A0[0][r]);
        A1[0][r] = gt[1][0] * A1[0][r];
        A1[0][r] = fmaf(gt[1][1], A1[1][r], A1[0][r]);
        A1[0][r] = fmaf(gt[1][2], A1[2][r], A1[0][r]);
    }

    // ---- di-reduction in LDS (v12 layout: rt*4096 + (n*2+mt)*1024 + qd*256 + lane*4) ----
    __syncthreads();
    float* red = (float*)smem;
    const int rbase = rt * 4096 + lane * 4;
#define EPI_STORE(ACC, N)                                                        \
    _Pragma("unroll")                                                            \
    for (int qd = 0; qd < 4; ++qd) {                                             \
        v4f vv; vv[0] = ACC[0][qd * 4]; vv[1] = ACC[0][qd * 4 + 1];              \
        vv[2] = ACC[0][qd * 4 + 2]; vv[3] = ACC[0][qd * 4 + 3];                  \
        *(v4f*)&red[rbase + ((N) * 2 + mt) * 1024 + qd * 256] = vv;              \
    }
#define EPI_ADD(ACC, N)                                                          \
    _Pragma("unroll")                                                            \
    for (int qd = 0; qd < 4; ++qd) {                                             \
        v4f vv = *(const v4f*)&red[rbase + ((N) * 2 + mt) * 1024 + qd * 256];    \
        vv[0] += ACC[0][qd * 4];     vv[1] += ACC[0][qd * 4 + 1];                \
        vv[2] += ACC[0][qd * 4 + 2]; vv[3] += ACC[0][qd * 4 + 3];                \
        *(v4f*)&red[rbase + ((N) * 2 + mt) * 1024 + qd * 256] = vv;              \
    }
    if (di == 2) { EPI_STORE(A0, 0) EPI_STORE(A1, 1) }
    __syncthreads();
    if (di == 1) { EPI_ADD(A0, 0) EPI_ADD(A1, 1) }
    __syncthreads();
    if (di == 0) {
        float* ob = out + (size_t)b * 262144 + (h0 + rt) * 64;
#define EPI_OUT(ACC, N)                                                          \
    _Pragma("unroll")                                                            \
    for (int qd = 0; qd < 4; ++qd) {                                             \
        const v4f vv = *(const v4f*)&red[rbase + ((N) * 2 + mt) * 1024 + qd * 256]; \
        _Pragma("unroll")                                                        \
        for (int j = 0; j < 4; ++j) {                                            \
            const int rg = qd * 4 + j;                                           \
            const int o = mt * 32 + (rg & 3) + 8 * (rg >> 2) + 4 * half;         \
            ob[(size_t)o * 4096 + (N) * 32 + l31] = ACC[0][rg] + vv[j];          \
        }                                                                        \
    }
        EPI_OUT(A0, 0) EPI_OUT(A1, 1)
    }
}

extern "C" void kernel_launch(void* const* d_in, const int* in_sizes, int n_in,
                              void* d_out, int out_size, void* d_ws, size_t ws_size,
                              hipStream_t stream) {
    const float* x      = (const float*)d_in[0];
    const float* depth  = (const float*)d_in[1];
    const float* weight = (const float*)d_in[2];
    float* out = (float*)d_out;

    unsigned short* wtb = (unsigned short*)d_ws;   // 589,824 B weight staging

    prep_weights<<<1152, 256, 0, stream>>>(weight, wtb);
    depthconv_v16<<<256, 768, 0, stream>>>(x, depth, wtb, out);
}